// Round 3
// baseline (213.913 us; speedup 1.0000x reference)
//
#include <hip/hip_runtime.h>
#include <hip/hip_cooperative_groups.h>
#include <cstdint>

namespace cg = cooperative_groups;

#define DEVFN __device__ __forceinline__

struct U128 { unsigned long long lo, hi; };

// rotate right by s (1..127): bit q of result = bit (q+s)%128 of w
DEVFN U128 rotr128(U128 w, int s) {
    U128 r;
    if (s == 64) { r.lo = w.hi; r.hi = w.lo; return r; }
    if (s < 64) {
        r.lo = (w.lo >> s) | (w.hi << (64 - s));
        r.hi = (w.hi >> s) | (w.lo << (64 - s));
    } else {
        int t = s - 64;
        unsigned long long lo = w.hi, hi = w.lo;
        r.lo = (lo >> t) | (hi << (64 - t));
        r.hi = (hi >> t) | (lo << (64 - t));
    }
    return r;
}

// logical shift right by s (1..127)
DEVFN U128 shr128(U128 w, int s) {
    U128 r;
    if (s == 64) { r.lo = w.hi; r.hi = 0ull; return r; }
    if (s < 64) {
        r.lo = (w.lo >> s) | (w.hi << (64 - s));
        r.hi = w.hi >> s;
    } else {
        r.lo = w.hi >> (s - 64); r.hi = 0ull;
    }
    return r;
}

__global__ __launch_bounds__(256, 2) void fused_all(
    const int* __restrict__ x, const int* __restrict__ masks,
    const float* __restrict__ W0, const float* __restrict__ b0,
    const float* __restrict__ W1, const float* __restrict__ b1,
    const float* __restrict__ Wo, const float* __restrict__ bo,
    float* __restrict__ out, float* __restrict__ S,
    float* __restrict__ A2, float* __restrict__ G2,
    float* __restrict__ h0, float* __restrict__ z1part)
{
    cg::grid_group grid = cg::this_grid();
    const int bid = blockIdx.x;     // 512 blocks
    const int tid = threadIdx.x;    // 256 threads

    __shared__ unsigned long long mw[3][2];
    __shared__ float cA[64], cG[64];
    __shared__ float S4[4][128];
    __shared__ float Wt[32][64];
    __shared__ float Ht[64][32];
    __shared__ float red[4];

    // ---------------- Phase 1: W0 reduction + S ----------------
    // mask bit-words (task-independent)
    if (tid < 128) {
        int half = tid >> 6, lane = tid & 63;
        #pragma unroll
        for (int k = 0; k < 3; ++k) {
            unsigned long long bal = __ballot(masks[k * 128 + half * 64 + lane] & 1);
            if (lane == 0) mw[k][half] = bal;
        }
    }
    __syncthreads();

    for (int t = bid; t < 769; t += 512) {
        __syncthreads();              // protect cA/cG reuse across grid-stride tasks
        if (t == 768) {
            // S[b][r] = 2 * (r==0 ? pc_r : 128 - pc_r), pc_r = popcount(Dc^r(x_b))
            int b = tid >> 2;         // 64 rows
            int rc = tid & 3;         // 4 chunks of 32 r
            const int* xb = x + b * 128;
            U128 w; w.lo = 0ull; w.hi = 0ull;
            #pragma unroll
            for (int p = 0; p < 64; ++p) w.lo |= (unsigned long long)(xb[p] & 1) << p;
            #pragma unroll
            for (int p = 0; p < 64; ++p) w.hi |= (unsigned long long)(xb[64 + p] & 1) << p;
            int r0 = rc * 32;
            if (r0 & 32) { U128 tt = rotr128(w, 32); w.lo ^= tt.lo; w.hi ^= tt.hi; }
            if (r0 & 64) { U128 tt = rotr128(w, 64); w.lo ^= tt.lo; w.hi ^= tt.hi; }
            for (int rr = 0; rr < 32; ++rr) {
                int r = r0 + rr;
                int pc = __popcll(w.lo) + __popcll(w.hi);
                int sv = (r == 0) ? pc : (128 - pc);
                S[b * 128 + r] = (float)(2 * sv);
                U128 tt = rotr128(w, 1);
                w.lo ^= tt.lo; w.hi ^= tt.hi;
            }
        } else {
            int hc = t & 3;           // 4 chunks of 256 h
            int y  = t >> 2;          // 0..191 (r, segment)
            int r, jstart, jend, slice;
            if (y < 128) { r = y >> 1; slice = y & 1; jstart = slice * 64; jend = (slice == 0) ? 64 : (128 - r); }
            else         { r = y - 64;  slice = 0;    jstart = 0;          jend = 128 - r; }
            int h = hc * 256 + tid;

            if (tid < 64) {
                int j = jstart + tid;
                int c = 0;
                #pragma unroll
                for (int k = 0; k < 3; ++k) {
                    U128 m; m.lo = mw[k][0]; m.hi = mw[k][1];
                    #pragma unroll
                    for (int s = 1; s <= 64; s <<= 1) {
                        if (r & s) { U128 tt = shr128(m, s); m.lo ^= tt.lo; m.hi ^= tt.hi; }
                    }
                    int bit = (j < 64) ? (int)((m.lo >> j) & 1) : (int)((m.hi >> (j - 64)) & 1);
                    c += bit;
                }
                cA[tid] = 0.5f * (float)c - 1.0f;
                cG[tid] = (float)(2 - c) * (1.0f / 256.0f);
            }
            __syncthreads();

            int off = r * 128 - (r * (r - 1)) / 2;
            const float* p = W0 + (off + jstart) * 1024 + h;
            int L = jend - jstart;    // <= 64
            float accA = 0.f, accG = 0.f;
            #pragma unroll 8
            for (int j = 0; j < L; ++j) {
                float w = p[j * 1024];
                accA += cA[j] * w;
                accG += cG[j] * w;
            }
            int row = slice * 128 + r;
            A2[row * 1024 + h] = accA;
            G2[row * 1024 + h] = accG;
        }
    }
    grid.sync();

    // ---------------- Phase 2: h0 = relu(b0 + colsum(A) + S.G) ----------------
    if (bid < 256) {
        int hc = bid >> 4;            // 16 chunks of 64 h
        int bg = bid & 15;            // 16 groups of 4 b
        int hl = tid & 63, bl = tid >> 6;
        int h = hc * 64 + hl;
        int b = bg * 4 + bl;
        {
            int r = tid & 127, b2 = tid >> 7;   // 2 passes
            S4[b2][r]     = S[(bg * 4 + b2) * 128 + r];
            S4[b2 + 2][r] = S[(bg * 4 + b2 + 2) * 128 + r];
        }
        __syncthreads();
        float acc = b0[h];
        #pragma unroll 8
        for (int r = 0; r < 64; ++r) {
            float a = A2[r * 1024 + h] + A2[(128 + r) * 1024 + h];
            float g = G2[r * 1024 + h] + G2[(128 + r) * 1024 + h];
            acc += a + S4[bl][r] * g;
        }
        #pragma unroll 8
        for (int r = 64; r < 128; ++r) {
            acc += A2[r * 1024 + h] + S4[bl][r] * G2[r * 1024 + h];
        }
        h0[b * 1024 + h] = fmaxf(acc, 0.f);
    }
    grid.sync();

    // ---------------- Phase 3: split-K layer-2 partials ----------------
    {
        int kc = bid >> 4;            // 32 chunks of 32 k
        int hc = bid & 15;            // 16 chunks of 64 h
        #pragma unroll
        for (int i = 0; i < 8; ++i) {
            int idx = tid + i * 256;  // 0..2047
            int k_ = idx >> 6, h_ = idx & 63;
            Wt[k_][h_] = W1[(kc * 32 + k_) * 1024 + hc * 64 + h_];
            int b_ = idx >> 5, k2 = idx & 31;
            Ht[b_][k2] = h0[b_ * 1024 + kc * 32 + k2];
        }
        __syncthreads();
        int h = tid & 63, bg4 = tid >> 6;
        float acc[16];
        #pragma unroll
        for (int i = 0; i < 16; ++i) acc[i] = 0.f;
        for (int k = 0; k < 32; k += 4) {
            float w0_ = Wt[k][h], w1_ = Wt[k + 1][h], w2_ = Wt[k + 2][h], w3_ = Wt[k + 3][h];
            #pragma unroll
            for (int bb = 0; bb < 16; ++bb) {
                float4 hv = *(const float4*)&Ht[bg4 * 16 + bb][k];
                acc[bb] += hv.x * w0_ + hv.y * w1_ + hv.z * w2_ + hv.w * w3_;
            }
        }
        #pragma unroll
        for (int bb = 0; bb < 16; ++bb) {
            int b = bg4 * 16 + bb;
            z1part[(kc * 64 + b) * 1024 + hc * 64 + h] = acc[bb];
        }
    }
    grid.sync();

    // ---------------- Phase 4: out = relu(b1 + sum z1part) . Wo + bo ----------------
    if (bid < 64) {
        int b = bid;
        float acc = 0.f;
        #pragma unroll
        for (int i = 0; i < 4; ++i) {
            int h = tid + i * 256;
            float z = b1[h];
            #pragma unroll
            for (int kc = 0; kc < 32; ++kc) z += z1part[(kc * 64 + b) * 1024 + h];
            acc += fmaxf(z, 0.f) * Wo[h];
        }
        #pragma unroll
        for (int off = 32; off >= 1; off >>= 1) acc += __shfl_down(acc, off);
        if ((tid & 63) == 0) red[tid >> 6] = acc;
        __syncthreads();
        if (tid == 0) out[b] = red[0] + red[1] + red[2] + red[3] + bo[0];
    }
}

extern "C" void kernel_launch(void* const* d_in, const int* in_sizes, int n_in,
                              void* d_out, int out_size, void* d_ws, size_t ws_size,
                              hipStream_t stream) {
    const int*   x     = (const int*)d_in[0];    // (64,128) 0/1
    const int*   masks = (const int*)d_in[1];    // (3,128) 0/1
    const float* W0    = (const float*)d_in[2];  // (8256,1024)
    const float* b0    = (const float*)d_in[3];  // (1024)
    const float* W1    = (const float*)d_in[4];  // (1024,1024)
    const float* b1    = (const float*)d_in[5];  // (1024)
    const float* Wo    = (const float*)d_in[6];  // (1024,1)
    const float* bo    = (const float*)d_in[7];  // (1)
    float* out = (float*)d_out;                  // (64,1)

    char* ws = (char*)d_ws;
    float* S      = (float*)(ws);                      // 64*128*4      = 32 KB
    float* A2     = (float*)(ws + (32u   << 10));      // 192*1024*4    = 768 KB
    float* G2     = (float*)(ws + (800u  << 10));      // 192*1024*4    = 768 KB
    float* h0     = (float*)(ws + (1568u << 10));      // 64*1024*4     = 256 KB
    float* z1part = (float*)(ws + (1824u << 10));      // 32*64*1024*4  = 8 MB

    void* args[] = { (void*)&x, (void*)&masks, (void*)&W0, (void*)&b0,
                     (void*)&W1, (void*)&b1, (void*)&Wo, (void*)&bo,
                     (void*)&out, (void*)&S, (void*)&A2, (void*)&G2,
                     (void*)&h0, (void*)&z1part };
    hipLaunchCooperativeKernel((void*)fused_all, dim3(512), dim3(256), args, 0, stream);
}

// Round 4
// 46.159 us; speedup vs baseline: 4.6343x; 4.6343x over previous
//
#include <hip/hip_runtime.h>
#include <cstdint>

#define DEVFN __device__ __forceinline__

struct U128 { unsigned long long lo, hi; };

// rotate right by s (1..127)
DEVFN U128 rotr128(U128 w, int s) {
    U128 r;
    if (s == 64) { r.lo = w.hi; r.hi = w.lo; return r; }
    if (s < 64) {
        r.lo = (w.lo >> s) | (w.hi << (64 - s));
        r.hi = (w.hi >> s) | (w.lo << (64 - s));
    } else {
        int t = s - 64;
        unsigned long long lo = w.hi, hi = w.lo;
        r.lo = (lo >> t) | (hi << (64 - t));
        r.hi = (hi >> t) | (lo << (64 - t));
    }
    return r;
}

// logical shift right by s (1..127)
DEVFN U128 shr128(U128 w, int s) {
    U128 r;
    if (s == 64) { r.lo = w.hi; r.hi = 0ull; return r; }
    if (s < 64) {
        r.lo = (w.lo >> s) | (w.hi << (64 - s));
        r.hi = w.hi >> s;
    } else {
        r.lo = w.hi >> (s - 64); r.hi = 0ull;
    }
    return r;
}

// cumulative task count: f(L) = sum_{l=1..L} ceil(l/32)
DEVFN int fcum(int L) { int q = L >> 5, s = L & 31; return 16 * q * (q + 1) + s * (q + 1); }
// first task index for level r (tasks ordered by r, then 32-wide j-chunks)
DEVFN int tstart(int r) { return 320 - fcum(128 - r); }

// K1: W0 reduction into 320 task rows + S computation (block 320).
// Task t -> (r, c): rows of the XOR-triangle level r, j in [32c, min(32c+32,128-r)).
// Each block reads its W0 rows CONTIGUOUSLY (thread = float4 of h).
__global__ __launch_bounds__(256) void k1_reduce(const int* __restrict__ x,
                                                 const int* __restrict__ masks,
                                                 const float* __restrict__ W0,
                                                 float* __restrict__ S,
                                                 float* __restrict__ A2,
                                                 float* __restrict__ G2) {
    int bid = blockIdx.x;
    int tid = threadIdx.x;

    if (bid == 320) {
        // S[b][r] = 2 * (r==0 ? pc_r : 128 - pc_r), pc_r = popcount(Dc^r(x_b))
        int b = tid >> 2;        // 64 rows
        int rc = tid & 3;        // 4 chunks of 32 r
        const int* xb = x + b * 128;
        U128 w; w.lo = 0ull; w.hi = 0ull;
        #pragma unroll
        for (int p = 0; p < 64; ++p) w.lo |= (unsigned long long)(xb[p] & 1) << p;
        #pragma unroll
        for (int p = 0; p < 64; ++p) w.hi |= (unsigned long long)(xb[64 + p] & 1) << p;
        int r0 = rc * 32;
        if (r0 & 32) { U128 tt = rotr128(w, 32); w.lo ^= tt.lo; w.hi ^= tt.hi; }
        if (r0 & 64) { U128 tt = rotr128(w, 64); w.lo ^= tt.lo; w.hi ^= tt.hi; }
        for (int rr = 0; rr < 32; ++rr) {
            int r = r0 + rr;
            int pc = __popcll(w.lo) + __popcll(w.hi);
            int sv = (r == 0) ? pc : (128 - pc);
            S[b * 128 + r] = (float)(2 * sv);
            U128 tt = rotr128(w, 1);
            w.lo ^= tt.lo; w.hi ^= tt.hi;
        }
        return;
    }

    // decode task id -> (r, c) : largest r with tstart(r) <= bid
    int lo = 0, hi = 127;
    while (lo < hi) { int mid = (lo + hi + 1) >> 1; if (tstart(mid) <= bid) lo = mid; else hi = mid - 1; }
    int r = lo;
    int c = bid - tstart(r);
    int j0 = c * 32;
    int L = 128 - r - j0; if (L > 32) L = 32;

    __shared__ unsigned long long mw[3][2];
    __shared__ float cA[32], cG[32];

    if (tid < 128) {
        int half = tid >> 6, lane = tid & 63;
        #pragma unroll
        for (int k = 0; k < 3; ++k) {
            unsigned long long bal = __ballot(masks[k * 128 + half * 64 + lane] & 1);
            if (lane == 0) mw[k][half] = bal;
        }
    }
    __syncthreads();
    if (tid < 32) {
        int j = j0 + tid;
        int cc = 0;
        #pragma unroll
        for (int k = 0; k < 3; ++k) {
            U128 m; m.lo = mw[k][0]; m.hi = mw[k][1];
            #pragma unroll
            for (int s = 1; s <= 64; s <<= 1) {
                if (r & s) { U128 tt = shr128(m, s); m.lo ^= tt.lo; m.hi ^= tt.hi; }
            }
            int bit = (j < 64) ? (int)((m.lo >> j) & 1) : (int)((m.hi >> (j - 64)) & 1);
            cc += bit;
        }
        cA[tid] = 0.5f * (float)cc - 1.0f;
        cG[tid] = (float)(2 - cc) * (1.0f / 256.0f);
    }
    __syncthreads();

    int rowoff = r * 128 - (r * (r - 1)) / 2 + j0;   // first W0 row of this task
    const float4* p = (const float4*)(W0 + (size_t)rowoff * 1024) + tid;
    float4 aA = {0.f, 0.f, 0.f, 0.f}, aG = {0.f, 0.f, 0.f, 0.f};
    #pragma unroll 4
    for (int jj = 0; jj < L; ++jj) {
        float4 v = p[jj * 256];
        float ca = cA[jj], cg = cG[jj];
        aA.x += ca * v.x; aA.y += ca * v.y; aA.z += ca * v.z; aA.w += ca * v.w;
        aG.x += cg * v.x; aG.y += cg * v.y; aG.z += cg * v.z; aG.w += cg * v.w;
    }
    ((float4*)(A2 + (size_t)bid * 1024))[tid] = aA;
    ((float4*)(G2 + (size_t)bid * 1024))[tid] = aG;
}

// K2: h0[b][h] = relu(b0[h] + sum_rows (A2[row][h] + S[b][r(row)] * G2[row][h]))
// grid: (32 h-chunks of 32) x (8 b-tiles of 8); thread = (h, b)
__global__ __launch_bounds__(256) void k2_h0(const float* __restrict__ A2,
                                             const float* __restrict__ G2,
                                             const float* __restrict__ S,
                                             const float* __restrict__ b0,
                                             float* __restrict__ h0) {
    int hc = blockIdx.x;          // 0..31
    int bt = blockIdx.y;          // 0..7
    int tid = threadIdx.x;
    int hl = tid & 31, bl = tid >> 5;
    int h = hc * 32 + hl;
    int b = bt * 8 + bl;

    __shared__ float Sblk[8][128];
    __shared__ int   rtab[320];

    #pragma unroll
    for (int i = 0; i < 4; ++i) {
        int idx = tid + i * 256;
        int bb = idx >> 7, rr = idx & 127;
        Sblk[bb][rr] = S[(bt * 8 + bb) * 128 + rr];
    }
    if (tid < 128) {
        int r = tid;
        int s0 = tstart(r);
        int n = (128 - r + 31) >> 5;
        for (int c = 0; c < n; ++c) rtab[s0 + c] = r;
    }
    __syncthreads();

    float acc = b0[h];
    #pragma unroll 8
    for (int row = 0; row < 320; ++row) {
        float a = A2[row * 1024 + h];
        float g = G2[row * 1024 + h];
        acc += a + Sblk[bl][rtab[row]] * g;
    }
    h0[b * 1024 + h] = fmaxf(acc, 0.f);
}

// K3: split-K GEMM partials: z1part[kc][b][h] = sum_{k in chunk} h0[b][k] * W1[k][h]
__global__ __launch_bounds__(256) void k3_layer2(const float* __restrict__ h0,
                                                 const float* __restrict__ W1,
                                                 float* __restrict__ z1part) {
    int hc = blockIdx.x;           // 16 (64 h each)
    int kc = blockIdx.y;           // 16 (64 k each)
    int tid = threadIdx.x;
    __shared__ float Wt[64][64];   // [k][h]
    __shared__ float Ht[64][64];   // [b][k]
    #pragma unroll
    for (int i = 0; i < 16; ++i) {
        int idx = tid + i * 256;
        int a = idx >> 6, c = idx & 63;
        Wt[a][c] = W1[(kc * 64 + a) * 1024 + hc * 64 + c];
        Ht[a][c] = h0[a * 1024 + kc * 64 + c];
    }
    __syncthreads();
    int h = tid & 63, bg = tid >> 6;    // 4 b-groups x 16 b
    float acc[16];
    #pragma unroll
    for (int i = 0; i < 16; ++i) acc[i] = 0.f;
    for (int k = 0; k < 64; k += 4) {
        float w0_ = Wt[k][h], w1_ = Wt[k + 1][h], w2_ = Wt[k + 2][h], w3_ = Wt[k + 3][h];
        #pragma unroll
        for (int bb = 0; bb < 16; ++bb) {
            float4 hv = *(const float4*)&Ht[bg * 16 + bb][k];
            acc[bb] += hv.x * w0_ + hv.y * w1_ + hv.z * w2_ + hv.w * w3_;
        }
    }
    #pragma unroll
    for (int bb = 0; bb < 16; ++bb) {
        int b = bg * 16 + bb;
        z1part[(kc * 64 + b) * 1024 + hc * 64 + h] = acc[bb];
    }
}

// K4: out[b] = sum_h relu(b1[h] + sum_kc z1part[kc][b][h]) * Wo[h] + bo
__global__ __launch_bounds__(256) void k4_out(const float* __restrict__ z1part,
                                              const float* __restrict__ b1,
                                              const float* __restrict__ Wo,
                                              const float* __restrict__ bo,
                                              float* __restrict__ out) {
    int b = blockIdx.x;
    int tid = threadIdx.x;
    float acc = 0.f;
    #pragma unroll
    for (int i = 0; i < 4; ++i) {
        int h = tid + i * 256;
        float z = b1[h];
        #pragma unroll
        for (int kc = 0; kc < 16; ++kc) z += z1part[(kc * 64 + b) * 1024 + h];
        acc += fmaxf(z, 0.f) * Wo[h];
    }
    #pragma unroll
    for (int off = 32; off >= 1; off >>= 1) acc += __shfl_down(acc, off);
    __shared__ float red[4];
    if ((tid & 63) == 0) red[tid >> 6] = acc;
    __syncthreads();
    if (tid == 0) out[b] = red[0] + red[1] + red[2] + red[3] + bo[0];
}

extern "C" void kernel_launch(void* const* d_in, const int* in_sizes, int n_in,
                              void* d_out, int out_size, void* d_ws, size_t ws_size,
                              hipStream_t stream) {
    const int*   x     = (const int*)d_in[0];    // (64,128) 0/1
    const int*   masks = (const int*)d_in[1];    // (3,128) 0/1
    const float* W0    = (const float*)d_in[2];  // (8256,1024)
    const float* b0    = (const float*)d_in[3];  // (1024)
    const float* W1    = (const float*)d_in[4];  // (1024,1024)
    const float* b1    = (const float*)d_in[5];  // (1024)
    const float* Wo    = (const float*)d_in[6];  // (1024,1)
    const float* bo    = (const float*)d_in[7];  // (1)
    float* out = (float*)d_out;                  // (64,1)

    char* ws = (char*)d_ws;
    float* S      = (float*)(ws);                      // 64*128*4      = 32 KB
    float* A2     = (float*)(ws + (32u   << 10));      // 320*1024*4    = 1280 KB
    float* G2     = (float*)(ws + (1312u << 10));      // 320*1024*4    = 1280 KB
    float* h0     = (float*)(ws + (2592u << 10));      // 64*1024*4     = 256 KB
    float* z1part = (float*)(ws + (2848u << 10));      // 16*64*1024*4  = 4 MB

    k1_reduce<<<321, 256, 0, stream>>>(x, masks, W0, S, A2, G2);
    k2_h0<<<dim3(32, 8), 256, 0, stream>>>(A2, G2, S, b0, h0);
    k3_layer2<<<dim3(16, 16), 256, 0, stream>>>(h0, W1, z1part);
    k4_out<<<64, 256, 0, stream>>>(z1part, b1, Wo, bo, out);
}